// Round 1
// baseline (863.392 us; speedup 1.0000x reference)
//
#include <hip/hip_runtime.h>
#include <hip/hip_cooperative_groups.h>
#include <math.h>

namespace cg = cooperative_groups;

// Round 9: persistent cooperative mega-kernel. All 6 stages of R8 fused into
// ONE dispatch with grid.sync() between stages — removes ~75us of inter-launch
// gaps (25% of R8 wall). Stage bodies are identical to R8; additionally the
// tiny Mt GEMM (64 blocks) now runs CONCURRENTLY with the Vt GEMM (512 blocks)
// since Vt doesn't depend on Mt.
//   S1 prep   : X->f16 || Wq,Wk bf16-split || Wv transpose->f16   (1024 blocks)
//   S2 mt||vt : Mt = Wk_s Wq_s^T (blocks 0..63)  ||  Vt = (Xf.Wv)^T (64..575)
//   S3 t      : T = Xf.Mt^T (blocks 0..511)
//   S4 scores : Sc = T . Xf^T -> fp32 (1024 blocks)
//   S5 softmax: P = softmax(Sc) -> f16 (8 rows/block)
//   S6 pv     : out = P . Vt^T (blocks 0..511)
// Grid 1024 = 256 CU x 4 blocks; LDS 33280*4 = 130KB/CU < 160KB;
// __launch_bounds__(256,4) caps VGPR at 128 (body needs 92) => co-resident.
// Fallback: if hipLaunchCooperativeKernel fails, run R8's 6-dispatch path.

typedef __bf16 bf16;
typedef _Float16 f16;
typedef __bf16 bf16x8 __attribute__((ext_vector_type(8)));
typedef __bf16 bf16x4 __attribute__((ext_vector_type(4)));
typedef _Float16 f16x4 __attribute__((ext_vector_type(4)));
typedef _Float16 f16x8 __attribute__((ext_vector_type(8)));
typedef float  f32x4  __attribute__((ext_vector_type(4)));

template<typename E> struct vec8_of;
template<> struct vec8_of<bf16> { using type = bf16x8; };
template<> struct vec8_of<f16>  { using type = f16x8; };

__device__ inline f32x4 mfma16(bf16x8 a, bf16x8 b, f32x4 c) {
    return __builtin_amdgcn_mfma_f32_16x16x32_bf16(a, b, c, 0, 0, 0);
}
__device__ inline f32x4 mfma16(f16x8 a, f16x8 b, f32x4 c) {
    return __builtin_amdgcn_mfma_f32_16x16x32_f16(a, b, c, 0, 0, 0);
}

#define AS1 __attribute__((address_space(1)))
#define AS3 __attribute__((address_space(3)))

template<typename E>
__device__ inline void async_load16(const E* g, void* l) {
    __builtin_amdgcn_global_load_lds((const AS1 unsigned int*)g,
                                     (AS3 unsigned int*)l, 16, 0, 0);
}

// C[M,N] = sum_k A[m,k]*B[n,k]  (B passed [N,K]-layout, leading dim ldb).
// SPLIT: hi/lo pairs, hh + hl + lh. BK: K-tile (32 split, 64 plain, swizzled).
// OUT_MODE: 0 fp32; 1 f16; 2 f16 transposed per-batch (V path).
template<typename E, bool SPLIT, int OUT_MODE, int BK>
__device__ __forceinline__ void gemm_body(
    char* __restrict__ smraw,
    const E* __restrict__ Ahi, const E* __restrict__ Alo,
    const E* __restrict__ Bhi, const E* __restrict__ Blo,
    float* __restrict__ Cf, f16* __restrict__ Ch,
    int K, int lda, int ldb, int ldc,
    long long sA, long long sB, long long sC,
    int bx, int by, int bz)
{
    using vec8 = typename vec8_of<E>::type;
    constexpr int TILE_BYTES = 128 * BK * (int)sizeof(E);   // 8192 or 16384
    constexpr int CPW = (TILE_BYTES / 1024) / 4;            // 1KB chunks per wave
    constexpr int SPR = (BK * (int)sizeof(E)) / 16;         // 16B slots per row
    constexpr int SWZ = (SPR == 8) ? 7 : 0;                 // swizzle mask (BK=64)

    Ahi += (long long)bz * sA;
    Bhi += (long long)bz * sB;
    if (SPLIT) { Alo += (long long)bz * sA; Blo += (long long)bz * sB; }

    const int tid  = threadIdx.x;
    const int lane = tid & 63;
    const int wave = tid >> 6;
    const int quad = lane >> 4;
    const int l16  = lane & 15;
    const int wm   = (wave >> 1) * 64;
    const int wn   = (wave & 1) * 64;

    const long long rowA0 = (long long)by * 128;
    const long long colB0 = (long long)bx * 128;

    int ofs[CPW], rr[CPW], cc8[CPW];
#pragma unroll
    for (int u = 0; u < CPW; u++) {
        ofs[u] = (wave * CPW + u) * 1024 + lane * 16;
        const int s = ofs[u] >> 4;
        rr[u]  = s / SPR;
        cc8[u] = (s & (SPR - 1)) ^ (rr[u] & SWZ);
    }

    f32x4 acc[4][4];
#pragma unroll
    for (int i = 0; i < 4; i++)
#pragma unroll
        for (int j = 0; j < 4; j++) acc[i][j] = (f32x4){0.f, 0.f, 0.f, 0.f};

    for (int k0 = 0; k0 < K; k0 += BK) {
#pragma unroll
        for (int u = 0; u < CPW; u++) {
            async_load16(Ahi + (rowA0 + rr[u]) * lda + k0 + cc8[u] * 8, smraw + 0 * TILE_BYTES + ofs[u]);
            async_load16(Bhi + (colB0 + rr[u]) * ldb + k0 + cc8[u] * 8, smraw + 1 * TILE_BYTES + ofs[u]);
            if (SPLIT) {
                async_load16(Alo + (rowA0 + rr[u]) * lda + k0 + cc8[u] * 8, smraw + 2 * TILE_BYTES + ofs[u]);
                async_load16(Blo + (colB0 + rr[u]) * ldb + k0 + cc8[u] * 8, smraw + 3 * TILE_BYTES + ofs[u]);
            }
        }
        __syncthreads();

#pragma unroll
        for (int kh = 0; kh < BK / 32; kh++) {
            const int kc8 = kh * 4 + quad;    // 16B chunk index within row
            vec8 a_hi[4], b_hi[4], a_lo[4], b_lo[4];
#pragma unroll
            for (int i = 0; i < 4; i++) {
                const int ra = wm + i * 16 + l16;
                const int rb = wn + i * 16 + l16;
                const int oa = ra * (SPR * 16) + ((kc8 ^ (ra & SWZ)) << 4);
                const int ob = rb * (SPR * 16) + ((kc8 ^ (rb & SWZ)) << 4);
                a_hi[i] = *(const vec8*)(smraw + 0 * TILE_BYTES + oa);
                b_hi[i] = *(const vec8*)(smraw + 1 * TILE_BYTES + ob);
                if (SPLIT) {
                    a_lo[i] = *(const vec8*)(smraw + 2 * TILE_BYTES + oa);
                    b_lo[i] = *(const vec8*)(smraw + 3 * TILE_BYTES + ob);
                }
            }
#pragma unroll
            for (int i = 0; i < 4; i++)
#pragma unroll
                for (int j = 0; j < 4; j++) {
                    acc[i][j] = mfma16(a_hi[i], b_hi[j], acc[i][j]);
                    if (SPLIT) {
                        acc[i][j] = mfma16(a_hi[i], b_lo[j], acc[i][j]);
                        acc[i][j] = mfma16(a_lo[i], b_hi[j], acc[i][j]);
                    }
                }
        }
        __syncthreads();
    }

    if (OUT_MODE == 2) {
        auto tr = (f16(*)[130])smraw;    // 128 x 130 f16 = 33280 B
#pragma unroll
        for (int i = 0; i < 4; i++)
#pragma unroll
            for (int j = 0; j < 4; j++)
#pragma unroll
                for (int e = 0; e < 4; e++)
                    tr[wn + j * 16 + l16][wm + i * 16 + quad * 4 + e] = (f16)acc[i][j][e];
        __syncthreads();
        const int batch = (int)(rowA0 >> 11);
        const int rib   = (int)(rowA0 & 2047);
        const int c  = tid >> 1;
        const int r0 = (tid & 1) << 6;
        f16* vt = Ch + (long long)batch * 1024 * 2048 + (long long)(colB0 + c) * ldc + rib + r0;
#pragma unroll
        for (int u = 0; u < 64; u += 8)
            *(f16x8*)(vt + u) = *(const f16x8*)&tr[c][r0 + u];
        return;
    }

    const long long cOff = (long long)bz * sC +
                           (rowA0 + wm + quad * 4) * (long long)ldc + colB0 + wn + l16;
#pragma unroll
    for (int i = 0; i < 4; i++)
#pragma unroll
        for (int e = 0; e < 4; e++) {
            const long long ro = cOff + (i * 16 + e) * ldc;
            if (OUT_MODE == 0) {
                float* rp = Cf + ro;
#pragma unroll
                for (int j = 0; j < 4; j++) rp[j * 16] = acc[i][j][e];
            } else {
                f16* rp = Ch + ro;
#pragma unroll
                for (int j = 0; j < 4; j++) rp[j * 16] = (f16)acc[i][j][e];
            }
        }
}

// ---- prep unit (one R8 prep_all block's worth of work)
__device__ __forceinline__ void prep_unit(
    int u, int tid, char* smraw,
    const float* __restrict__ X, f16* __restrict__ Xf,
    const float* __restrict__ Wq, const float* __restrict__ Wk,
    const float* __restrict__ Wv,
    bf16* __restrict__ Wq_h, bf16* __restrict__ Wq_l,
    bf16* __restrict__ Wk_h, bf16* __restrict__ Wk_l,
    f16* __restrict__ Wvt_f)
{
    if (u < 8192) {
        long long i = (long long)u * 256 + tid;
        float4 v = ((const float4*)X)[i];
        f16x4 fv = {(f16)v.x, (f16)v.y, (f16)v.z, (f16)v.w};
        *(f16x4*)(Xf + 4 * i) = fv;
    } else if (u < 10240) {
        const int b2 = u - 8192;
        const float4* W = (const float4*)(b2 < 1024 ? Wq : Wk);
        bf16* hh = b2 < 1024 ? Wq_h : Wk_h;
        bf16* ll = b2 < 1024 ? Wq_l : Wk_l;
        long long i = (long long)(b2 & 1023) * 256 + tid;
        float4 v = W[i];
        bf16 a0 = (bf16)v.x, a1 = (bf16)v.y, a2 = (bf16)v.z, a3 = (bf16)v.w;
        bf16x4 hv = {a0, a1, a2, a3};
        bf16x4 lv = {(bf16)(v.x - (float)a0), (bf16)(v.y - (float)a1),
                     (bf16)(v.z - (float)a2), (bf16)(v.w - (float)a3)};
        *(bf16x4*)(hh + 4 * i) = hv;
        *(bf16x4*)(ll + 4 * i) = lv;
    } else {
        const int b3 = u - 10240;
        auto t = (float(*)[33])smraw;              // 32x33 f32 = 4224 B in smraw
        const int bx = (b3 & 31) * 32, by = (b3 >> 5) * 32;
        const int tx = tid & 31, ty = tid >> 5;
#pragma unroll
        for (int i = 0; i < 32; i += 8)
            t[ty + i][tx] = Wv[(long long)(by + ty + i) * 1024 + bx + tx];
        __syncthreads();
#pragma unroll
        for (int i = 0; i < 32; i += 8) {
            long long o = (long long)(bx + ty + i) * 1024 + by + tx;
            Wvt_f[o] = (f16)t[tx][ty + i];
        }
    }
}

// ---- softmax of one 2048-wide fp32 row -> f16 (LDS `red` lives in smraw)
__device__ __forceinline__ void softmax_row(
    const float* __restrict__ S, f16* __restrict__ P,
    long long row, int tid, char* smraw)
{
    float* red = (float*)smraw;
    const float* p = S + row * 2048;
    f16* q = P + row * 2048;
    const int wv = tid >> 6, lane = tid & 63;

    float v[8];
    float m = -3.4e38f;
#pragma unroll
    for (int i = 0; i < 8; i++) { v[i] = p[tid + (i << 8)]; m = fmaxf(m, v[i]); }
#pragma unroll
    for (int off = 32; off > 0; off >>= 1) m = fmaxf(m, __shfl_xor(m, off, 64));

    __syncthreads();                 // protect red from previous row / stage
    if (lane == 0) red[wv] = m;
    __syncthreads();
    m = fmaxf(fmaxf(red[0], red[1]), fmaxf(red[2], red[3]));

    float s = 0.f;
#pragma unroll
    for (int i = 0; i < 8; i++) { v[i] = __expf(v[i] - m); s += v[i]; }
#pragma unroll
    for (int off = 32; off > 0; off >>= 1) s += __shfl_xor(s, off, 64);
    __syncthreads();
    if (lane == 0) red[wv] = s;
    __syncthreads();
    s = red[0] + red[1] + red[2] + red[3];

    const float inv = 1.0f / s;
#pragma unroll
    for (int i = 0; i < 8; i++) q[tid + (i << 8)] = (f16)(v[i] * inv);
}

// ================= persistent cooperative mega-kernel =================
__global__ __launch_bounds__(256, 4) void attention_mega(
    const float* __restrict__ X, const float* __restrict__ Wq,
    const float* __restrict__ Wk, const float* __restrict__ Wv,
    float* __restrict__ out, f16* __restrict__ Xf,
    bf16* __restrict__ Wq_h, bf16* __restrict__ Wq_l,
    bf16* __restrict__ Wk_h, bf16* __restrict__ Wk_l,
    f16* __restrict__ Wvt_f, f16* __restrict__ Mt_f,
    f16* __restrict__ T, f16* __restrict__ Vt,
    float* __restrict__ Sc, f16* __restrict__ P)
{
    extern __shared__ char smraw[];
    const int b   = blockIdx.x;      // 0..1023
    const int tid = threadIdx.x;
    cg::grid_group grid = cg::this_grid();

    // S1: prep — 11264 units over 1024 blocks (11 each: 8 X, Wq, Wk, Wv-tr)
    for (int u = b; u < 11264; u += 1024)
        prep_unit(u, tid, smraw, X, Xf, Wq, Wk, Wv,
                  Wq_h, Wq_l, Wk_h, Wk_l, Wvt_f);
    grid.sync();

    // S2: Mt (split bf16, blocks 0..63)  ||  Vt = (Xf.Wv)^T (blocks 64..575)
    if (b < 64) {
        gemm_body<bf16, true, 1, 32>(smraw, Wk_h, Wk_l, Wq_h, Wq_l,
                                     nullptr, Mt_f, 1024, 1024, 1024, 1024,
                                     0, 0, 0, b & 7, b >> 3, 0);
    } else if (b < 576) {
        const int u = b - 64;        // 0..511 -> (bx,by) of 8x64 Vt tiles
        gemm_body<f16, false, 2, 64>(smraw, Xf, nullptr, Wvt_f, nullptr,
                                     nullptr, Vt, 1024, 1024, 1024, 2048,
                                     0, 0, 0, u & 7, u >> 3, 0);
    }
    grid.sync();

    // S3: T = Xf . Mt^T (blocks 0..511, 8x64 tiles)
    if (b < 512)
        gemm_body<f16, false, 1, 64>(smraw, Xf, nullptr, Mt_f, nullptr,
                                     nullptr, T, 1024, 1024, 1024, 1024,
                                     0, 0, 0, b & 7, b >> 3, 0);
    grid.sync();

    // S4: Sc = T . Xf^T per batch -> fp32 (1024 blocks = 16x16x4)
    gemm_body<f16, false, 0, 64>(smraw, T, nullptr, Xf, nullptr, Sc, nullptr,
                                 1024, 1024, 1024, 2048,
                                 2048LL * 1024, 2048LL * 1024, 2048LL * 2048,
                                 b & 15, (b >> 4) & 15, b >> 8);
    grid.sync();

    // S5: softmax — 8 rows per block
    for (int i = 0; i < 8; i++)
        softmax_row(Sc, P, (long long)b * 8 + i, tid, smraw);
    grid.sync();

    // S6: out = P . Vt^T (blocks 0..511 = 8x16x4)
    if (b < 512)
        gemm_body<f16, false, 0, 64>(smraw, P, nullptr, Vt, nullptr, out, nullptr,
                                     2048, 2048, 2048, 1024,
                                     2048LL * 2048, 1024LL * 2048, 2048LL * 1024,
                                     b & 7, (b >> 3) & 15, b >> 7);
}

// ================= R8 fallback kernels (used only if coop launch fails) ====
__global__ __launch_bounds__(256) void prep_all(
    const float4* __restrict__ X, f16* __restrict__ Xf,
    const float* __restrict__ Wq, const float* __restrict__ Wk, const float* __restrict__ Wv,
    bf16* __restrict__ Wq_h, bf16* __restrict__ Wq_l,
    bf16* __restrict__ Wk_h, bf16* __restrict__ Wk_l,
    f16* __restrict__ Wvt_f)
{
    int b = blockIdx.x;
    if (b < 8192) {
        long long i = (long long)b * 256 + threadIdx.x;
        float4 v = X[i];
        f16x4 fv = {(f16)v.x, (f16)v.y, (f16)v.z, (f16)v.w};
        *(f16x4*)(Xf + 4 * i) = fv;
    } else if (b < 10240) {
        const int b2 = b - 8192;
        const float4* W = (const float4*)(b2 < 1024 ? Wq : Wk);
        bf16* hh = b2 < 1024 ? Wq_h : Wk_h;
        bf16* ll = b2 < 1024 ? Wq_l : Wk_l;
        long long i = (long long)(b2 & 1023) * 256 + threadIdx.x;
        float4 v = W[i];
        bf16 a0 = (bf16)v.x, a1 = (bf16)v.y, a2 = (bf16)v.z, a3 = (bf16)v.w;
        bf16x4 hv = {a0, a1, a2, a3};
        bf16x4 lv = {(bf16)(v.x - (float)a0), (bf16)(v.y - (float)a1),
                     (bf16)(v.z - (float)a2), (bf16)(v.w - (float)a3)};
        *(bf16x4*)(hh + 4 * i) = hv;
        *(bf16x4*)(ll + 4 * i) = lv;
    } else {
        const int b3 = b - 10240;
        __shared__ float t[32][33];
        const int bx = (b3 & 31) * 32, by = (b3 >> 5) * 32;
        const int tx = threadIdx.x & 31, ty = threadIdx.x >> 5;
#pragma unroll
        for (int i = 0; i < 32; i += 8)
            t[ty + i][tx] = Wv[(long long)(by + ty + i) * 1024 + bx + tx];
        __syncthreads();
#pragma unroll
        for (int i = 0; i < 32; i += 8) {
            long long o = (long long)(bx + ty + i) * 1024 + by + tx;
            Wvt_f[o] = (f16)t[tx][ty + i];
        }
    }
}

__global__ __launch_bounds__(256) void tv_gemm(
    const f16* __restrict__ Xf, const f16* __restrict__ Mt_f,
    const f16* __restrict__ Wvt_f,
    f16* __restrict__ T, f16* __restrict__ Vt)
{
    extern __shared__ char smraw[];
    if (blockIdx.x < 8)
        gemm_body<f16, false, 1, 64>(smraw, Xf, nullptr, Mt_f, nullptr,
                                     nullptr, T, 1024, 1024, 1024, 1024,
                                     0, 0, 0, blockIdx.x, blockIdx.y, 0);
    else
        gemm_body<f16, false, 2, 64>(smraw, Xf, nullptr, Wvt_f, nullptr,
                                     nullptr, Vt, 1024, 1024, 1024, 2048,
                                     0, 0, 0, blockIdx.x - 8, blockIdx.y, 0);
}

template<typename E, bool SPLIT, int OUT_MODE, int BK>
__global__ __launch_bounds__(256) void gemm_bt(
    const E* __restrict__ Ahi, const E* __restrict__ Alo,
    const E* __restrict__ Bhi, const E* __restrict__ Blo,
    float* __restrict__ Cf, f16* __restrict__ Ch,
    int K, int lda, int ldb, int ldc,
    long long sA, long long sB, long long sC)
{
    extern __shared__ char smraw[];
    gemm_body<E, SPLIT, OUT_MODE, BK>(smraw, Ahi, Alo, Bhi, Blo, Cf, Ch,
                                      K, lda, ldb, ldc, sA, sB, sC,
                                      blockIdx.x, blockIdx.y, blockIdx.z);
}

__global__ __launch_bounds__(256) void softmax_f16(const float* __restrict__ S,
                                                   f16* __restrict__ P, int n)
{
    const long long row = blockIdx.x;
    const float* p = S + row * (long long)n;
    f16* q = P + row * (long long)n;
    const int tid = threadIdx.x;
    const int wv = tid >> 6, lane = tid & 63;

    float v[8];
    float m = -3.4e38f;
#pragma unroll
    for (int i = 0; i < 8; i++) { v[i] = p[tid + (i << 8)]; m = fmaxf(m, v[i]); }
#pragma unroll
    for (int off = 32; off > 0; off >>= 1) m = fmaxf(m, __shfl_xor(m, off, 64));

    __shared__ float red[4];
    if (lane == 0) red[wv] = m;
    __syncthreads();
    m = fmaxf(fmaxf(red[0], red[1]), fmaxf(red[2], red[3]));

    float s = 0.f;
#pragma unroll
    for (int i = 0; i < 8; i++) { v[i] = __expf(v[i] - m); s += v[i]; }
#pragma unroll
    for (int off = 32; off > 0; off >>= 1) s += __shfl_xor(s, off, 64);
    __syncthreads();
    if (lane == 0) red[wv] = s;
    __syncthreads();
    s = red[0] + red[1] + red[2] + red[3];

    const float inv = 1.0f / s;
#pragma unroll
    for (int i = 0; i < 8; i++) q[tid + (i << 8)] = (f16)(v[i] * inv);
}

extern "C" void kernel_launch(void* const* d_in, const int* in_sizes, int n_in,
                              void* d_out, int out_size, void* d_ws, size_t ws_size,
                              hipStream_t stream) {
    const float* X  = (const float*)d_in[0];   // [8192,1024]
    const float* Wq = (const float*)d_in[1];   // [1024,1024]
    const float* Wk = (const float*)d_in[2];
    const float* Wv = (const float*)d_in[3];
    float* out = (float*)d_out;                // [8192,1024]

    char* w = (char*)d_ws;
    const long long MB = 1024LL * 1024;
    f16*  Xf    = (f16*) (w + 0 * MB);     // 16 MB
    bf16* Wq_h  = (bf16*)(w + 16 * MB);    // 2 MB
    bf16* Wq_l  = (bf16*)(w + 18 * MB);
    bf16* Wk_h  = (bf16*)(w + 20 * MB);
    bf16* Wk_l  = (bf16*)(w + 22 * MB);
    f16*  Wvt_f = (f16*) (w + 24 * MB);    // 2 MB (transposed)
    f16*  Mt_f  = (f16*) (w + 26 * MB);    // 2 MB
    f16*  T     = (f16*) (w + 28 * MB);    // 16 MB [8192,1024]
    f16*  Vt    = (f16*) (w + 44 * MB);    // 16 MB [4][1024][2048]
    float* Sc   = (float*)(w + 60 * MB);   // 64 MB
    f16*  P     = (f16*) (w + 124 * MB);   // 32 MB -> ends 156 MB

    // ---- single cooperative dispatch (grid 1024 = 256 CU x 4 blocks) ----
    void* kargs[] = { (void*)&X, (void*)&Wq, (void*)&Wk, (void*)&Wv,
                      (void*)&out, (void*)&Xf,
                      (void*)&Wq_h, (void*)&Wq_l, (void*)&Wk_h, (void*)&Wk_l,
                      (void*)&Wvt_f, (void*)&Mt_f, (void*)&T, (void*)&Vt,
                      (void*)&Sc, (void*)&P };
    hipError_t err = hipLaunchCooperativeKernel(
        reinterpret_cast<void*>(attention_mega),
        dim3(1024), dim3(256), kargs, 33280, stream);
    if (err == hipSuccess) return;

    // ---- fallback: R8's verified 6-dispatch path ----
    dim3 blk(256);
    prep_all<<<dim3(11264), blk, 0, stream>>>(
        (const float4*)X, Xf, Wq, Wk, Wv, Wq_h, Wq_l, Wk_h, Wk_l, Wvt_f);
    gemm_bt<bf16, true, 1, 32><<<dim3(8, 8, 1), blk, 32768, stream>>>(
        Wk_h, Wk_l, Wq_h, Wq_l, nullptr, Mt_f,
        1024, 1024, 1024, 1024, 0, 0, 0);
    tv_gemm<<<dim3(16, 64, 1), blk, 33280, stream>>>(Xf, Mt_f, Wvt_f, T, Vt);
    gemm_bt<f16, false, 0, 64><<<dim3(16, 16, 4), blk, 32768, stream>>>(
        T, nullptr, Xf, nullptr, Sc, nullptr,
        1024, 1024, 1024, 2048,
        2048LL * 1024, 2048LL * 1024, 2048LL * 2048);
    softmax_f16<<<dim3(4 * 2048), blk, 0, stream>>>(Sc, P, 2048);
    gemm_bt<f16, false, 0, 64><<<dim3(8, 16, 4), blk, 32768, stream>>>(
        P, nullptr, Vt, nullptr, out, nullptr,
        2048, 2048, 2048, 1024,
        2048LL * 2048, 1024LL * 2048, 2048LL * 1024);
}

// Round 2
// 302.752 us; speedup vs baseline: 2.8518x; 2.8518x over previous
//
#include <hip/hip_runtime.h>
#include <math.h>

// Round 10: revert to verified R8 6-dispatch structure (coop mega-kernel was a
// 2.9x regression: grid.sync spin ~580us + VGPR squeeze). This round attacks
// GEMM interiors: BK=32 double-buffered LDS with counted-vmcnt prefetch
// (T3/T4 minimum-2-phase): stage(t+1) issued BEFORE compute(t), raw s_barrier
// + s_waitcnt vmcnt(4) instead of __syncthreads' full vmcnt(0) drain.
// Also: SPR=4 swizzle slot^((r>>1)&3) fixes Mt's latent 8-way bank conflict,
// and softmax gets float4/f16x4 vector I/O.
//   D1 prep_all : X->f16 || Wq,Wk bf16-split || Wv transpose->f16
//   D2 mt       : Mt = Wk_s Wq_s^T (split-bf16 3-MFMA, single-buffer) -> f16
//   D3 tv_gemm  : T = Xf.Mt^T (bx<8) || Vt = (Xf.Wv)^T (bx>=8), f16 DBUF
//   D4 scores   : Sc = T . Xf^T -> fp32, f16 DBUF
//   D5 softmax  : P = softmax(Sc) -> f16 (vectorized)
//   D6 pv       : out = P . Vt^T, f16 DBUF

typedef __bf16 bf16;
typedef _Float16 f16;
typedef __bf16 bf16x8 __attribute__((ext_vector_type(8)));
typedef __bf16 bf16x4 __attribute__((ext_vector_type(4)));
typedef _Float16 f16x4 __attribute__((ext_vector_type(4)));
typedef _Float16 f16x8 __attribute__((ext_vector_type(8)));
typedef float  f32x4  __attribute__((ext_vector_type(4)));

template<typename E> struct vec8_of;
template<> struct vec8_of<bf16> { using type = bf16x8; };
template<> struct vec8_of<f16>  { using type = f16x8; };

__device__ inline f32x4 mfma16(bf16x8 a, bf16x8 b, f32x4 c) {
    return __builtin_amdgcn_mfma_f32_16x16x32_bf16(a, b, c, 0, 0, 0);
}
__device__ inline f32x4 mfma16(f16x8 a, f16x8 b, f32x4 c) {
    return __builtin_amdgcn_mfma_f32_16x16x32_f16(a, b, c, 0, 0, 0);
}

#define AS1 __attribute__((address_space(1)))
#define AS3 __attribute__((address_space(3)))

template<typename E>
__device__ inline void async_load16(const E* g, void* l) {
    __builtin_amdgcn_global_load_lds((const AS1 unsigned int*)g,
                                     (AS3 unsigned int*)l, 16, 0, 0);
}

// C[M,N] = sum_k A[m,k]*B[n,k]  (B passed [N,K]-layout, leading dim ldb).
// SPLIT: hi/lo pairs, hh + hl + lh (single-buffered, __syncthreads path).
// DBUF : double-buffered LDS, counted-vmcnt prefetch (f16 BK=32 only).
// OUT_MODE: 0 fp32; 1 f16; 2 f16 transposed per-batch (V path).
// Swizzle: SPR==8 -> slot^(r&7); SPR==4 -> slot^((r>>1)&3). Involution applied
// on the staging global-source side AND the LDS read side (rule both-or-neither).
template<typename E, bool SPLIT, int OUT_MODE, int BK, bool DBUF>
__device__ __forceinline__ void gemm_body(
    char* __restrict__ smraw,
    const E* __restrict__ Ahi, const E* __restrict__ Alo,
    const E* __restrict__ Bhi, const E* __restrict__ Blo,
    float* __restrict__ Cf, f16* __restrict__ Ch,
    int K, int lda, int ldb, int ldc,
    long long sA, long long sB, long long sC,
    int bx, int by, int bz)
{
    using vec8 = typename vec8_of<E>::type;
    constexpr int TILE_BYTES = 128 * BK * (int)sizeof(E);   // 8192 @ BK=32
    constexpr int CPW = (TILE_BYTES / 1024) / 4;            // 1KB chunks per wave
    constexpr int SPR = (BK * (int)sizeof(E)) / 16;         // 16B slots per row
    constexpr int NMAT = SPLIT ? 4 : 2;
    static_assert(!DBUF || (CPW == 2 && !SPLIT), "DBUF assumes 4 loads/stage");

    Ahi += (long long)bz * sA;
    Bhi += (long long)bz * sB;
    if (SPLIT) { Alo += (long long)bz * sA; Blo += (long long)bz * sB; }

    const int tid  = threadIdx.x;
    const int lane = tid & 63;
    const int wave = tid >> 6;
    const int quad = lane >> 4;
    const int l16  = lane & 15;
    const int wm   = (wave >> 1) * 64;
    const int wn   = (wave & 1) * 64;

    const long long rowA0 = (long long)by * 128;
    const long long colB0 = (long long)bx * 128;

    auto swz = [](int r) -> int { return (SPR == 8) ? (r & 7) : ((r >> 1) & 3); };

    int ofs[CPW], rr[CPW], cc8[CPW];
#pragma unroll
    for (int u = 0; u < CPW; u++) {
        ofs[u] = (wave * CPW + u) * 1024 + lane * 16;
        const int s = ofs[u] >> 4;
        rr[u]  = s / SPR;
        cc8[u] = (s & (SPR - 1)) ^ swz(rr[u]);
    }

    f32x4 acc[4][4];
#pragma unroll
    for (int i = 0; i < 4; i++)
#pragma unroll
        for (int j = 0; j < 4; j++) acc[i][j] = (f32x4){0.f, 0.f, 0.f, 0.f};

    auto stage = [&](int k0, int buf) {
        char* base = smraw + buf * (NMAT * TILE_BYTES);
#pragma unroll
        for (int u = 0; u < CPW; u++) {
            async_load16(Ahi + (rowA0 + rr[u]) * lda + k0 + cc8[u] * 8, base + 0 * TILE_BYTES + ofs[u]);
            async_load16(Bhi + (colB0 + rr[u]) * ldb + k0 + cc8[u] * 8, base + 1 * TILE_BYTES + ofs[u]);
            if (SPLIT) {
                async_load16(Alo + (rowA0 + rr[u]) * lda + k0 + cc8[u] * 8, base + 2 * TILE_BYTES + ofs[u]);
                async_load16(Blo + (colB0 + rr[u]) * ldb + k0 + cc8[u] * 8, base + 3 * TILE_BYTES + ofs[u]);
            }
        }
    };

    auto compute = [&](int buf) {
        char* base = smraw + buf * (NMAT * TILE_BYTES);
#pragma unroll
        for (int kh = 0; kh < BK / 32; kh++) {
            const int kc8 = kh * 4 + quad;    // 16B chunk index within row
            vec8 a_hi[4], b_hi[4], a_lo[4], b_lo[4];
#pragma unroll
            for (int i = 0; i < 4; i++) {
                const int ra = wm + i * 16 + l16;
                const int rb = wn + i * 16 + l16;
                const int oa = ra * (SPR * 16) + ((kc8 ^ swz(ra)) << 4);
                const int ob = rb * (SPR * 16) + ((kc8 ^ swz(rb)) << 4);
                a_hi[i] = *(const vec8*)(base + 0 * TILE_BYTES + oa);
                b_hi[i] = *(const vec8*)(base + 1 * TILE_BYTES + ob);
                if (SPLIT) {
                    a_lo[i] = *(const vec8*)(base + 2 * TILE_BYTES + oa);
                    b_lo[i] = *(const vec8*)(base + 3 * TILE_BYTES + ob);
                }
            }
#pragma unroll
            for (int i = 0; i < 4; i++)
#pragma unroll
                for (int j = 0; j < 4; j++) {
                    acc[i][j] = mfma16(a_hi[i], b_hi[j], acc[i][j]);
                    if (SPLIT) {
                        acc[i][j] = mfma16(a_hi[i], b_lo[j], acc[i][j]);
                        acc[i][j] = mfma16(a_lo[i], b_hi[j], acc[i][j]);
                    }
                }
        }
    };

    if (DBUF) {
        const int nt = K / BK;
        stage(0, 0);
        for (int t = 0; t < nt; t++) {
            const int cur = t & 1;
            if (t + 1 < nt) {
                stage((t + 1) * BK, cur ^ 1);
                asm volatile("s_waitcnt vmcnt(4)" ::: "memory");   // tile t landed; t+1 in flight
            } else {
                asm volatile("s_waitcnt vmcnt(0)" ::: "memory");
            }
            __builtin_amdgcn_s_barrier();            // buf[cur] ready for all waves
            asm volatile("" ::: "memory");
            compute(cur);
            asm volatile("s_waitcnt lgkmcnt(0)" ::: "memory");     // own ds_reads landed
            __builtin_amdgcn_sched_barrier(0);
            __builtin_amdgcn_s_barrier();            // all waves done reading buf[cur]
            asm volatile("" ::: "memory");
        }
    } else {
        for (int k0 = 0; k0 < K; k0 += BK) {
            stage(k0, 0);
            __syncthreads();
            compute(0);
            __syncthreads();
        }
    }

    if (OUT_MODE == 2) {
        auto tr = (f16(*)[130])smraw;    // 128 x 130 f16 = 33280 B
#pragma unroll
        for (int i = 0; i < 4; i++)
#pragma unroll
            for (int j = 0; j < 4; j++)
#pragma unroll
                for (int e = 0; e < 4; e++)
                    tr[wn + j * 16 + l16][wm + i * 16 + quad * 4 + e] = (f16)acc[i][j][e];
        __syncthreads();
        const int batch = (int)(rowA0 >> 11);
        const int rib   = (int)(rowA0 & 2047);
        const int c  = tid >> 1;
        const int r0 = (tid & 1) << 6;
        f16* vt = Ch + (long long)batch * 1024 * 2048 + (long long)(colB0 + c) * ldc + rib + r0;
#pragma unroll
        for (int u = 0; u < 64; u += 8)
            *(f16x8*)(vt + u) = *(const f16x8*)&tr[c][r0 + u];
        return;
    }

    const long long cOff = (long long)bz * sC +
                           (rowA0 + wm + quad * 4) * (long long)ldc + colB0 + wn + l16;
#pragma unroll
    for (int i = 0; i < 4; i++)
#pragma unroll
        for (int e = 0; e < 4; e++) {
            const long long ro = cOff + (i * 16 + e) * ldc;
            if (OUT_MODE == 0) {
                float* rp = Cf + ro;
#pragma unroll
                for (int j = 0; j < 4; j++) rp[j * 16] = acc[i][j][e];
            } else {
                f16* rp = Ch + ro;
#pragma unroll
                for (int j = 0; j < 4; j++) rp[j * 16] = (f16)acc[i][j][e];
            }
        }
}

// ---- D1: blocks 0..8191 X->f16; 8192..10239 Wq/Wk bf16-split (natural);
//          10240..11263 Wv transpose -> f16.
__global__ __launch_bounds__(256) void prep_all(
    const float4* __restrict__ X, f16* __restrict__ Xf,
    const float* __restrict__ Wq, const float* __restrict__ Wk, const float* __restrict__ Wv,
    bf16* __restrict__ Wq_h, bf16* __restrict__ Wq_l,
    bf16* __restrict__ Wk_h, bf16* __restrict__ Wk_l,
    f16* __restrict__ Wvt_f)
{
    int b = blockIdx.x;
    if (b < 8192) {
        long long i = (long long)b * 256 + threadIdx.x;
        float4 v = X[i];
        f16x4 fv = {(f16)v.x, (f16)v.y, (f16)v.z, (f16)v.w};
        *(f16x4*)(Xf + 4 * i) = fv;
    } else if (b < 10240) {
        const int b2 = b - 8192;
        const float4* W = (const float4*)(b2 < 1024 ? Wq : Wk);
        bf16* hh = b2 < 1024 ? Wq_h : Wk_h;
        bf16* ll = b2 < 1024 ? Wq_l : Wk_l;
        long long i = (long long)(b2 & 1023) * 256 + threadIdx.x;
        float4 v = W[i];
        bf16 a0 = (bf16)v.x, a1 = (bf16)v.y, a2 = (bf16)v.z, a3 = (bf16)v.w;
        bf16x4 hv = {a0, a1, a2, a3};
        bf16x4 lv = {(bf16)(v.x - (float)a0), (bf16)(v.y - (float)a1),
                     (bf16)(v.z - (float)a2), (bf16)(v.w - (float)a3)};
        *(bf16x4*)(hh + 4 * i) = hv;
        *(bf16x4*)(ll + 4 * i) = lv;
    } else {
        const int b3 = b - 10240;
        __shared__ float t[32][33];
        const int bx = (b3 & 31) * 32, by = (b3 >> 5) * 32;
        const int tx = threadIdx.x & 31, ty = threadIdx.x >> 5;
#pragma unroll
        for (int i = 0; i < 32; i += 8)
            t[ty + i][tx] = Wv[(long long)(by + ty + i) * 1024 + bx + tx];
        __syncthreads();
#pragma unroll
        for (int i = 0; i < 32; i += 8) {
            long long o = (long long)(bx + ty + i) * 1024 + by + tx;
            Wvt_f[o] = (f16)t[tx][ty + i];
        }
    }
}

// ---- D3: T = Xf.Mt^T (bx<8) || Vt = (Xf.Wv)^T (bx>=8). f16 BK=32 DBUF.
__global__ __launch_bounds__(256) void tv_gemm(
    const f16* __restrict__ Xf, const f16* __restrict__ Mt_f,
    const f16* __restrict__ Wvt_f,
    f16* __restrict__ T, f16* __restrict__ Vt)
{
    extern __shared__ char smraw[];
    if (blockIdx.x < 8)
        gemm_body<f16, false, 1, 32, true>(smraw, Xf, nullptr, Mt_f, nullptr,
                                           nullptr, T, 1024, 1024, 1024, 1024,
                                           0, 0, 0, blockIdx.x, blockIdx.y, 0);
    else
        gemm_body<f16, false, 2, 32, true>(smraw, Xf, nullptr, Wvt_f, nullptr,
                                           nullptr, Vt, 1024, 1024, 1024, 2048,
                                           0, 0, 0, blockIdx.x - 8, blockIdx.y, 0);
}

// ---- generic GEMM wrapper (D2, D4, D6)
template<typename E, bool SPLIT, int OUT_MODE, int BK, bool DBUF>
__global__ __launch_bounds__(256) void gemm_bt(
    const E* __restrict__ Ahi, const E* __restrict__ Alo,
    const E* __restrict__ Bhi, const E* __restrict__ Blo,
    float* __restrict__ Cf, f16* __restrict__ Ch,
    int K, int lda, int ldb, int ldc,
    long long sA, long long sB, long long sC)
{
    extern __shared__ char smraw[];
    gemm_body<E, SPLIT, OUT_MODE, BK, DBUF>(smraw, Ahi, Alo, Bhi, Blo, Cf, Ch,
                                            K, lda, ldb, ldc, sA, sB, sC,
                                            blockIdx.x, blockIdx.y, blockIdx.z);
}

// ---- D5: row softmax fp32 -> f16, vectorized (float4 in, f16x4 out).
__global__ __launch_bounds__(256) void softmax_f16(const float* __restrict__ S,
                                                   f16* __restrict__ P, int n)
{
    const long long row = blockIdx.x;
    const float4* p = (const float4*)(S + row * (long long)n);   // 512 float4
    f16* q = P + row * (long long)n;
    const int tid = threadIdx.x;
    const int wv = tid >> 6, lane = tid & 63;

    float4 va = p[tid], vb = p[tid + 256];
    float v[8] = {va.x, va.y, va.z, va.w, vb.x, vb.y, vb.z, vb.w};
    float m = -3.4e38f;
#pragma unroll
    for (int i = 0; i < 8; i++) m = fmaxf(m, v[i]);
#pragma unroll
    for (int off = 32; off > 0; off >>= 1) m = fmaxf(m, __shfl_xor(m, off, 64));

    __shared__ float red[4];
    if (lane == 0) red[wv] = m;
    __syncthreads();
    m = fmaxf(fmaxf(red[0], red[1]), fmaxf(red[2], red[3]));

    float s = 0.f;
#pragma unroll
    for (int i = 0; i < 8; i++) { v[i] = __expf(v[i] - m); s += v[i]; }
#pragma unroll
    for (int off = 32; off > 0; off >>= 1) s += __shfl_xor(s, off, 64);
    __syncthreads();
    if (lane == 0) red[wv] = s;
    __syncthreads();
    s = red[0] + red[1] + red[2] + red[3];

    const float inv = 1.0f / s;
    f16x4 o0 = {(f16)(v[0] * inv), (f16)(v[1] * inv), (f16)(v[2] * inv), (f16)(v[3] * inv)};
    f16x4 o1 = {(f16)(v[4] * inv), (f16)(v[5] * inv), (f16)(v[6] * inv), (f16)(v[7] * inv)};
    *(f16x4*)(q + tid * 4) = o0;
    *(f16x4*)(q + 1024 + tid * 4) = o1;
}

extern "C" void kernel_launch(void* const* d_in, const int* in_sizes, int n_in,
                              void* d_out, int out_size, void* d_ws, size_t ws_size,
                              hipStream_t stream) {
    const float* X  = (const float*)d_in[0];   // [8192,1024]
    const float* Wq = (const float*)d_in[1];   // [1024,1024]
    const float* Wk = (const float*)d_in[2];
    const float* Wv = (const float*)d_in[3];
    float* out = (float*)d_out;                // [8192,1024]

    char* w = (char*)d_ws;
    const long long MB = 1024LL * 1024;
    f16*  Xf    = (f16*) (w + 0 * MB);     // 16 MB
    bf16* Wq_h  = (bf16*)(w + 16 * MB);    // 2 MB
    bf16* Wq_l  = (bf16*)(w + 18 * MB);
    bf16* Wk_h  = (bf16*)(w + 20 * MB);
    bf16* Wk_l  = (bf16*)(w + 22 * MB);
    f16*  Wvt_f = (f16*) (w + 24 * MB);    // 2 MB (transposed)
    f16*  Mt_f  = (f16*) (w + 26 * MB);    // 2 MB
    f16*  T     = (f16*) (w + 28 * MB);    // 16 MB [8192,1024]
    f16*  Vt    = (f16*) (w + 44 * MB);    // 16 MB [4][1024][2048]
    float* Sc   = (float*)(w + 60 * MB);   // 64 MB
    f16*  P     = (f16*) (w + 124 * MB);   // 32 MB -> ends 156 MB

    dim3 blk(256);

    // D1: X->f16 || Wq,Wk split || Wv transpose->f16
    prep_all<<<dim3(11264), blk, 0, stream>>>(
        (const float4*)X, Xf, Wq, Wk, Wv, Wq_h, Wq_l, Wk_h, Wk_l, Wvt_f);

    // D2: Mt = Wk_s Wq_s^T (split bf16, 3-MFMA, single-buffer) -> f16
    gemm_bt<bf16, true, 1, 32, false><<<dim3(8, 8, 1), blk, 32768, stream>>>(
        Wk_h, Wk_l, Wq_h, Wq_l, nullptr, Mt_f,
        1024, 1024, 1024, 1024, 0, 0, 0);

    // D3: T || Vt (f16 BK=32 DBUF; 33280 B LDS for the V transpose)
    tv_gemm<<<dim3(16, 64, 1), blk, 33280, stream>>>(Xf, Mt_f, Wvt_f, T, Vt);

    // D4: Sc = T . Xf^T per batch -> fp32
    gemm_bt<f16, false, 0, 32, true><<<dim3(16, 16, 4), blk, 32768, stream>>>(
        T, nullptr, Xf, nullptr, Sc, nullptr,
        1024, 1024, 1024, 2048,
        2048LL * 1024, 2048LL * 1024, 2048LL * 2048);

    // D5: softmax rows -> f16 P
    softmax_f16<<<dim3(4 * 2048), blk, 0, stream>>>(Sc, P, 2048);

    // D6: out = P . Vt^T
    gemm_bt<f16, false, 0, 32, true><<<dim3(8, 16, 4), blk, 32768, stream>>>(
        P, nullptr, Vt, nullptr, out, nullptr,
        2048, 2048, 2048, 1024,
        2048LL * 2048, 1024LL * 2048, 2048LL * 1024);
}